// Round 1
// baseline (552.581 us; speedup 1.0000x reference)
//
#include <hip/hip_runtime.h>
#include <hip/hip_bf16.h>

#define GRID9 9
#define S 81          // STATE_NUM
#define HID 32
#define OBS (2*S)

// One block per batch element b. 128 threads = 2 waves.
//  phase 1: t<81 gathers nsc[i] (diagonal band of action_count), served=min(nsc,demand)
//  phase 2: wave0 (t<64) reduces immediate_reward; wave1 lanes (t-64<32) compute h1
//  phase 3: t<32 computes h2, dot with W3, shuffle-reduce -> next_return
__global__ __launch_bounds__(128) void vpn_fused(
    const float* __restrict__ obs,
    const float* __restrict__ A,     // (B, 81, 81)
    const float* __restrict__ W1,    // (81, 32)
    const float* __restrict__ W2,    // (32, 32)
    const float* __restrict__ W3,    // (32, 1)
    const float* __restrict__ b3,    // (1,)
    float* __restrict__ out,         // [sv(B) | imm(B) | nr(B) | nsc(B*81)]
    int B_)
{
    const int b = blockIdx.x;
    const int t = threadIdx.x;

    __shared__ float nsc_s[S];
    __shared__ float served_s[S];
    __shared__ float h1_s[HID];
    __shared__ float imm_s;

    const float* __restrict__ Ab = A + (size_t)b * (S * S);

    if (t < S) {
        const int r = t / GRID9;
        const int c = t - r * GRID9;
        // nsc[b,t] = sum over j in {t, t-9, t+9, t-1, t+1} (valid) of A[b, j, t]
        float v = Ab[t * S + t];
        if (r > 0)         v += Ab[(t - GRID9) * S + t];
        if (r < GRID9 - 1) v += Ab[(t + GRID9) * S + t];
        if (c > 0)         v += Ab[(t - 1) * S + t];
        if (c < GRID9 - 1) v += Ab[(t + 1) * S + t];
        nsc_s[t] = v;
        const float d = obs[(size_t)b * OBS + S + t];
        served_s[t] = fminf(v, d);
        // nsc output block
        out[(size_t)3 * B_ + (size_t)b * S + t] = v;
    }
    __syncthreads();

    if (t < 64) {
        // wave 0: reduce immediate_reward over 81 served values
        float s = served_s[t];
        if (t + 64 < S) s += served_s[t + 64];
        #pragma unroll
        for (int off = 32; off > 0; off >>= 1)
            s += __shfl_down(s, off);
        if (t == 0) imm_s = s;
    } else if (t < 64 + HID) {
        // wave 1: h1[k] = relu(nsc @ W1)
        const int k = t - 64;
        float acc = 0.f;
        #pragma unroll 9
        for (int i = 0; i < S; ++i)
            acc += nsc_s[i] * W1[i * HID + k];
        h1_s[k] = fmaxf(acc, 0.f);
    }
    __syncthreads();

    if (t < HID) {
        const int k = t;
        float acc = 0.f;
        #pragma unroll
        for (int j = 0; j < HID; ++j)
            acc += h1_s[j] * W2[j * HID + k];
        const float h2 = fmaxf(acc, 0.f);
        float v = h2 * W3[k];
        #pragma unroll
        for (int off = 16; off > 0; off >>= 1)
            v += __shfl_down(v, off, 32);
        if (k == 0) {
            const float nr  = v + b3[0];
            const float imm = imm_s;
            out[b]              = imm + nr;   // symbolic_val
            out[B_ + b]         = imm;        // immediate_reward
            out[2 * B_ + b]     = nr;         // next_return
        }
    }
}

extern "C" void kernel_launch(void* const* d_in, const int* in_sizes, int n_in,
                              void* d_out, int out_size, void* d_ws, size_t ws_size,
                              hipStream_t stream) {
    const float* obs = (const float*)d_in[0];
    const float* A   = (const float*)d_in[1];
    const float* W1  = (const float*)d_in[2];
    const float* W2  = (const float*)d_in[3];
    const float* W3  = (const float*)d_in[4];
    const float* b3  = (const float*)d_in[5];
    // inflow_src/act/seg (d_in[6..8]) are compile-time derivable; unused.

    const int B_ = in_sizes[0] / OBS;   // 16384
    float* out = (float*)d_out;

    vpn_fused<<<B_, 128, 0, stream>>>(obs, A, W1, W2, W3, b3, out, B_);
}